// Round 6
// baseline (873.549 us; speedup 1.0000x reference)
//
#include <hip/hip_runtime.h>
#include <hip/hip_fp16.h>
#include <cstdint>
#include <cstddef>

typedef _Float16 f16;
typedef _Float16 f16x8 __attribute__((ext_vector_type(8)));
typedef _Float16 f16x4 __attribute__((ext_vector_type(4)));
typedef _Float16 f16x2 __attribute__((ext_vector_type(2)));
typedef float f32x4 __attribute__((ext_vector_type(4)));
typedef unsigned int ui4 __attribute__((ext_vector_type(4)));

#define NB 64
#define SEQ 512
#define HDIM 1024
#define NHEAD 8
#define HD 128
#define MR (NB * SEQ)      // 32768 rows
#define QK_LD 2048         // q,k packed rows (v goes straight to vT)

// async 16B/lane global->LDS. LDS dest = wave-uniform base + lane*16.
__device__ __forceinline__ void async_copy16(const f16* g, f16* l) {
  __builtin_amdgcn_global_load_lds(
      (__attribute__((address_space(1))) void*)(void*)const_cast<f16*>(g),
      (__attribute__((address_space(3))) void*)l, 16, 0, 0);
}

// ---------------- merged prep kernel #1 ----------------
// block ranges:
//  [0,1): conv mean reduce -> cs
//  [1,513): transpose_cast w1 [512,1024] -> w1T [1024,512]
//  [513,5633): 5x transpose_cast 1024^2 (w2, wq*g, wk*g, wv*g, wp)
//  [5633,6657): cast wo -> f16
//  [6657,6669): concat bq,bk,bv -> bqkv
//  [6669,6701): fuse_bias p1 (bo . wp partials)
//  [6701,6797): c-partials: cpart[jc][n] = {sum g_k W[k,n], sum lnb_k W[k,n]}
__global__ __launch_bounds__(256) void prep1(
    const float* __restrict__ cw, const float* __restrict__ cb, float* __restrict__ cs,
    const float* __restrict__ w1, f16* __restrict__ w1T,
    const float* __restrict__ w2, const float* __restrict__ wq,
    const float* __restrict__ wk, const float* __restrict__ wv,
    const float* __restrict__ wp,
    f16* __restrict__ w2T, f16* __restrict__ qkvT, f16* __restrict__ wpT,
    const float* __restrict__ wo, f16* __restrict__ woh,
    const float* __restrict__ bq, const float* __restrict__ bk,
    const float* __restrict__ bv, float* __restrict__ bqkv,
    const float* __restrict__ bo, float* __restrict__ part,
    const float* __restrict__ g, const float* __restrict__ lb,
    float2* __restrict__ cpart) {
  __shared__ float tile[32][33];
  __shared__ float sa[4], sb[4];
  const int b = blockIdx.x;
  const int tid = threadIdx.x;

  if (b == 0) {
    float a = 0.f, bb = 0.f;
    for (int i = tid; i < HDIM; i += 256) { a += cw[i]; bb += cb[i]; }
    for (int m = 32; m >= 1; m >>= 1) { a += __shfl_xor(a, m); bb += __shfl_xor(bb, m); }
    if ((tid & 63) == 0) { sa[tid >> 6] = a; sb[tid >> 6] = bb; }
    __syncthreads();
    if (tid == 0) {
      cs[0] = (sa[0] + sa[1] + sa[2] + sa[3]) * (1.f / HDIM);
      cs[1] = (sb[0] + sb[1] + sb[2] + sb[3]) * (1.f / HDIM);
    }
  } else if (b < 513) {
    int idx = b - 1;
    int bx = idx & 31, by = idx >> 5;              // 32 x 16
    int tx = tid & 31, ty = tid >> 5;
    int n0 = bx * 32, k0 = by * 32;
#pragma unroll
    for (int r = 0; r < 32; r += 8) tile[ty + r][tx] = w1[(size_t)(k0 + ty + r) * 1024 + n0 + tx];
    __syncthreads();
#pragma unroll
    for (int r = 0; r < 32; r += 8)
      w1T[(size_t)(n0 + ty + r) * 512 + k0 + tx] = (f16)tile[tx][ty + r];
  } else if (b < 5633) {
    int idx = b - 513;
    int z = idx >> 10, rem = idx & 1023;
    int bx = rem & 31, by = rem >> 5;              // 32 x 32
    const float* src; f16* dst; bool sc = false;
    switch (z) {
      case 0: src = w2; dst = w2T; break;
      case 1: src = wq; dst = qkvT; sc = true; break;
      case 2: src = wk; dst = qkvT + (size_t)1024 * 1024; sc = true; break;
      case 3: src = wv; dst = qkvT + (size_t)2048 * 1024; sc = true; break;
      default: src = wp; dst = wpT; break;
    }
    int tx = tid & 31, ty = tid >> 5;
    int n0 = bx * 32, k0 = by * 32;
#pragma unroll
    for (int r = 0; r < 32; r += 8) tile[ty + r][tx] = src[(size_t)(k0 + ty + r) * 1024 + n0 + tx];
    __syncthreads();
    float gk = sc ? g[k0 + tx] : 1.f;
#pragma unroll
    for (int r = 0; r < 32; r += 8)
      dst[(size_t)(n0 + ty + r) * 1024 + k0 + tx] = (f16)(tile[tx][ty + r] * gk);
  } else if (b < 6657) {
    size_t i = (size_t)(b - 5633) * 256 + tid;
    float4 v = ((const float4*)wo)[i];
    f16x4 o;
    o[0] = (f16)v.x; o[1] = (f16)v.y; o[2] = (f16)v.z; o[3] = (f16)v.w;
    ((f16x4*)woh)[i] = o;
  } else if (b < 6669) {
    int i = (b - 6657) * 256 + tid;  // 3072
    if (i < 1024) bqkv[i] = bq[i];
    else if (i < 2048) bqkv[i] = bk[i - 1024];
    else bqkv[i] = bv[i - 2048];
  } else if (b < 6701) {
    int idx = b - 6669;
    int nb = idx & 3, jc = idx >> 2;
    int n = nb * 256 + tid;
    float s = 0.f;
#pragma unroll 8
    for (int j = jc * 128; j < jc * 128 + 128; j++) s += bo[j] * wp[(size_t)j * 1024 + n];
    part[(size_t)jc * 1024 + n] = s;
  } else {
    int idx = b - 6701;                 // 0..95: nb 0..11, jc 0..7
    int nb = idx % 12, jc = idx / 12;
    int n = nb * 256 + tid;             // 0..3071
    int sel = n >> 10, col = n & 1023;
    const float* W = (sel == 0) ? wq : (sel == 1) ? wk : wv;
    float s1 = 0.f, s2 = 0.f;
#pragma unroll 4
    for (int k = jc * 128; k < jc * 128 + 128; k++) {
      float w = W[(size_t)k * 1024 + col];
      s1 += g[k] * w;
      s2 += lb[k] * w;
    }
    cpart[(size_t)jc * 3072 + n] = make_float2(s1, s2);
  }
}

// ---------------- merged prep kernel #2 ----------------
//  [0,16384): prep_x: xh = (x*(1+cs0)+cs1) f16
//  [16384,16388): bp2 finalize
//  [16388,16400): c12 finalize: c12[n] = {sum c1, sum c2 + bqkv[n]}
__global__ __launch_bounds__(256) void prep2(
    const float* __restrict__ x, const float* __restrict__ cs, f16* __restrict__ xh,
    const float* __restrict__ part, const float* __restrict__ bp, float* __restrict__ bp2,
    const float2* __restrict__ cpart, const float* __restrict__ bqkv,
    float2* __restrict__ c12) {
  const int b = blockIdx.x;
  const int tid = threadIdx.x;
  if (b < 16384) {
    size_t i = (size_t)b * 256 + tid;
    float cwv = 1.f + cs[0], cbv = cs[1];
    float4 v = ((const float4*)x)[i];
    f16x4 o;
    o[0] = (f16)(v.x * cwv + cbv);
    o[1] = (f16)(v.y * cwv + cbv);
    o[2] = (f16)(v.z * cwv + cbv);
    o[3] = (f16)(v.w * cwv + cbv);
    ((f16x4*)xh)[i] = o;
  } else if (b < 16388) {
    int n = (b - 16384) * 256 + tid;
    float s = bp[n];
#pragma unroll
    for (int jc = 0; jc < 8; jc++) s += part[(size_t)jc * 1024 + n];
    bp2[n] = s;
  } else {
    int n = (b - 16388) * 256 + tid;   // 0..3071
    float s1 = 0.f, s2 = 0.f;
#pragma unroll
    for (int jc = 0; jc < 8; jc++) {
      float2 p = cpart[(size_t)jc * 3072 + n];
      s1 += p.x; s2 += p.y;
    }
    c12[n] = make_float2(s1, s2 + bqkv[n]);
  }
}

// LayerNorm row stats over H=1024: stats[row] = {mu, rsqrt(var+eps)}
__global__ __launch_bounds__(256) void ln_stats(
    const f16* __restrict__ xin, float2* __restrict__ stats) {
  int row = blockIdx.x;
  int t = threadIdx.x;
  f16x4 vh = ((const f16x4*)(xin + (size_t)row * HDIM))[t];
  float vx = (float)vh[0], vy = (float)vh[1], vz = (float)vh[2], vw = (float)vh[3];
  float s = vx + vy + vz + vw;
  float s2 = vx * vx + vy * vy + vz * vz + vw * vw;
  for (int m = 32; m >= 1; m >>= 1) { s += __shfl_xor(s, m); s2 += __shfl_xor(s2, m); }
  __shared__ float sa[4], sb[4];
  if ((t & 63) == 0) { sa[t >> 6] = s; sb[t >> 6] = s2; }
  __syncthreads();
  if (t == 0) {
    float S = sa[0] + sa[1] + sa[2] + sa[3];
    float S2 = sb[0] + sb[1] + sb[2] + sb[3];
    float mu = S * (1.f / HDIM);
    float var = S2 * (1.f / HDIM) - mu * mu;
    stats[row] = make_float2(mu, rsqrtf(var + 1e-5f));
  }
}

// ---------------- main NT GEMM: C[M,N] = A[M,K] @ BT[N,K]^T + bias ----------------
// 512 threads / 8 waves (2x4 grid, wave tile 64x32), 128x128 block tile, BK=64.
// Rotated global_load_lds staging (bank-floor b128 reads, verified conflict-free).
// R0-proven configuration (858 TF, MfmaUtil 40%) -- K-loop untouched.
// EPI: 0 relu->f16 | 1 f16 | 4 f16 no-bias | 5 fp32 = acc+bias+(float)Xres (residual)
//      6 QKV with LN FOLDED: A = x_regh (raw), BT pre-scaled by ln_g;
//         v = inv_r*acc - inv_r*mu_r*c1[n] + c2[n]  (c12 = {c1,c2}, stats = {mu,inv})
//         cols<2048 -> f16 @ LD 2048; cols>=2048 -> V written to vT layout
template <int EPI>
__global__ __launch_bounds__(512) void gemm_nt(
    const f16* __restrict__ A, const f16* __restrict__ BT,
    const float* __restrict__ bias, void* __restrict__ Cout, int N, int K,
    const f16* __restrict__ Xres, f16* __restrict__ vTout,
    const float2* __restrict__ c12, const float2* __restrict__ stats) {
  __shared__ __align__(16) f16 As[128 * 64];
  __shared__ __align__(16) f16 Bs[128 * 64];
  const int tid = threadIdx.x;
  const int wave = tid >> 6, lane = tid & 63;
  const int l15 = lane & 15, quad = lane >> 4;

  // block swizzle: groups of up to 16 bm, bn inner
  const int gn = N >> 7;
  const int gm = (int)gridDim.x / gn;
  const int pid = blockIdx.x;
  const int npg = 16 * gn;
  const int gid = pid / npg;
  const int rem = pid - gid * npg;
  const int grows = min(16, gm - gid * 16);
  const int bm = gid * 16 + rem % grows;
  const int bn = rem / grows;

  const int wm = wave >> 2, wn = wave & 3;   // 2 x 4 wave grid; wave tile 64x32

  f32x4 z4 = {0.f, 0.f, 0.f, 0.f};
  f32x4 acc[4][2];
#pragma unroll
  for (int i = 0; i < 4; i++)
#pragma unroll
    for (int j = 0; j < 2; j++) acc[i][j] = z4;

  // staging: row = tid>>3 (0..63), phys chunk p = tid&7, logical c = (p - row&7)&7
  const int srow = tid >> 3;
  const int c = ((tid & 7) - (srow & 7)) & 7;
  const f16* Ag = A + (size_t)(bm * 128 + srow) * K + c * 8;
  const f16* Bg = BT + (size_t)(bn * 128 + srow) * K + c * 8;
  f16* Al0 = As + tid * 8;
  f16* Al1 = As + 64 * 64 + tid * 8;
  f16* Bl0 = Bs + tid * 8;
  f16* Bl1 = Bs + 64 * 64 + tid * 8;
  const size_t kstep = (size_t)64 * K;

  const int r7 = l15 & 7;  // fragment-row rotation

  for (int k0 = 0; k0 < K; k0 += 64) {
    async_copy16(Ag, Al0);
    async_copy16(Ag + kstep, Al1);
    async_copy16(Bg, Bl0);
    async_copy16(Bg + kstep, Bl1);
    Ag += 64; Bg += 64;
    __syncthreads();
#pragma unroll
    for (int s = 0; s < 2; s++) {
      f16x8 af[4], bfr[2];
#pragma unroll
      for (int t = 0; t < 4; t++) {
        int phys = (s * 4 + quad + r7) & 7;
        af[t] = *(const f16x8*)&As[(wm * 64 + t * 16 + l15) * 64 + phys * 8];
      }
#pragma unroll
      for (int u = 0; u < 2; u++) {
        int phys = (s * 4 + quad + r7) & 7;
        bfr[u] = *(const f16x8*)&Bs[(wn * 32 + u * 16 + l15) * 64 + phys * 8];
      }
#pragma unroll
      for (int i = 0; i < 4; i++)
#pragma unroll
        for (int j = 0; j < 2; j++)
          acc[i][j] = __builtin_amdgcn_mfma_f32_16x16x32_f16(af[i], bfr[j], acc[i][j], 0, 0, 0);
    }
    __syncthreads();
  }

  float* Cf = (float*)Cout;
  f16* Ch = (f16*)Cout;
#pragma unroll
  for (int i = 0; i < 4; i++) {
    int r0 = bm * 128 + wm * 64 + i * 16 + quad * 4;
    float av[4], bf2[4];
    if (EPI == 6) {
#pragma unroll
      for (int reg = 0; reg < 4; reg++) {
        float2 st = stats[r0 + reg];
        av[reg] = st.y;               // inv
        bf2[reg] = -st.y * st.x;      // -inv*mu
      }
    }
#pragma unroll
    for (int j = 0; j < 2; j++) {
      int c0 = bn * 128 + wn * 32 + j * 16;
      int cc = c0 + l15;
      float bv = (EPI == 4 || EPI == 6) ? 0.f : bias[cc];
      float2 cv;
      if (EPI == 6) cv = c12[cc];
      if (EPI == 6 && c0 >= 2048) {
        // V part -> vT[(b*8+h)*128 + d][m], 4 consecutive m per lane
        int hh = (cc - 2048) >> 7, d = (cc - 2048) & 127;
        int bb = r0 >> 9, ml = r0 & 511;
        f16x4 o;
#pragma unroll
        for (int reg = 0; reg < 4; reg++)
          o[reg] = (f16)(av[reg] * acc[i][j][reg] + bf2[reg] * cv.x + cv.y);
        *(f16x4*)&vTout[((size_t)(bb * NHEAD + hh) * HD + d) * SEQ + ml] = o;
      } else {
#pragma unroll
        for (int reg = 0; reg < 4; reg++) {
          float v;
          if (EPI == 6) v = av[reg] * acc[i][j][reg] + bf2[reg] * cv.x + cv.y;
          else          v = acc[i][j][reg] + bv;
          if (EPI == 0)      Ch[(size_t)(r0 + reg) * N + cc] = (f16)fmaxf(v, 0.f);
          else if (EPI == 1) Ch[(size_t)(r0 + reg) * N + cc] = (f16)v;
          else if (EPI == 4) Ch[(size_t)(r0 + reg) * N + cc] = (f16)v;
          else if (EPI == 5) {
            size_t idx = (size_t)(r0 + reg) * N + cc;
            Cf[idx] = v + (float)Xres[idx];
          } else {  // EPI == 6, q/k part, LD 2048
            Ch[(size_t)(r0 + reg) * QK_LD + cc] = (f16)v;
          }
        }
      }
    }
  }
}

// ---------------- flash attention, T12 in-register softmax + dbuf staging ----
// (R5 version, unchanged)
__global__ __launch_bounds__(512) void attn_kernel(
    const f16* __restrict__ qkv, const f16* __restrict__ vT,
    f16* __restrict__ ctx) {
  const int tid = threadIdx.x;
  const int wave = tid >> 6, lane = tid & 63;
  const int l15 = lane & 15, quad = lane >> 4;
  const int bidx = blockIdx.x;
  const int qc = bidx >> 9;            // siblings 512 apart -> same XCD, co-resident
  const int bh = bidx & 511;
  const int h = bh & 7, bb = bh >> 3;

  const f16* Qbase = qkv + (size_t)(bb * SEQ) * QK_LD + h * 128;
  const f16* Kbase = Qbase + 1024;
  const f16* VTbase = vT + (size_t)(bb * NHEAD + h) * HD * SEQ;

  __shared__ __align__(16) f16 Ks[2 * 64 * 128];    // double-buffered, rotated chunks
  __shared__ __align__(16) f16 VTs[2 * 128 * 64];   // double-buffered, rotated chunks

  const float scale = 0.08838834764831845f;  // 1/sqrt(128)
  const int qrow0 = qc * 256 + wave * 32;
  f16x8 qf[2][4];
#pragma unroll
  for (int tm = 0; tm < 2; tm++)
#pragma unroll
    for (int s = 0; s < 4; s++) {
      qf[tm][s] = *(const f16x8*)(Qbase + (size_t)(qrow0 + tm * 16 + l15) * QK_LD + s * 32 + quad * 8);
#pragma unroll
      for (int e = 0; e < 8; e++) qf[tm][s][e] *= (f16)scale;
    }

  f32x4 z4 = {0.f, 0.f, 0.f, 0.f};
  f32x4 O[2][8];
#pragma unroll
  for (int i = 0; i < 2; i++)
#pragma unroll
    for (int j = 0; j < 8; j++) O[i][j] = z4;
  float lrow[2] = {0.f, 0.f};   // row-sum for qrow = qrow0 + tm*16 + l15

  // K staging: row = 32*i + (tid>>4), p = tid&15, c = (p - row&15)&15
  const int kc = ((tid & 15) - ((tid >> 4) & 15)) & 15;
  const f16* Kg = Kbase + (size_t)(tid >> 4) * QK_LD + kc * 8;
  // VT staging: row = 64*i + (tid>>3), p = tid&7, c = (p - row&7)&7
  const int vc = ((tid & 7) - ((tid >> 3) & 7)) & 7;
  const f16* Vg = VTbase + (size_t)(tid >> 3) * SEQ + vc * 8;

  const int r7 = l15 & 7;
  const bool qodd = (quad & 1) != 0;

#define STAGE_KV_(BUF, KT) do {                                               \
    const int kr_ = (KT) * 64;                                                \
    _Pragma("unroll") for (int i_ = 0; i_ < 2; i_++)                          \
      async_copy16(Kg + (size_t)(kr_ + 32 * i_) * QK_LD,                      \
                   Ks + (BUF) * 8192 + tid * 8 + 4096 * i_);                  \
    _Pragma("unroll") for (int i_ = 0; i_ < 2; i_++)                          \
      async_copy16(Vg + (size_t)(64 * i_) * SEQ + kr_,                        \
                   VTs + (BUF) * 8192 + tid * 8 + 4096 * i_);                 \
  } while (0)

  // clean vmcnt base (Q-frag loads retired), then stage tile 0
  asm volatile("s_waitcnt vmcnt(0)" ::: "memory");
  STAGE_KV_(0, 0);

  for (int kt = 0; kt < 8; kt++) {
    const int buf = kt & 1;
    const f16* Ksb = Ks + buf * 8192;
    const f16* VTsb = VTs + buf * 8192;
    const int krow0 = kt * 64;

    if (kt < 7) {
      STAGE_KV_(buf ^ 1, kt + 1);
      asm volatile("s_waitcnt vmcnt(4)" ::: "memory");  // force tile kt, keep kt+1 in flight
    } else {
      asm volatile("s_waitcnt vmcnt(0)" ::: "memory");
    }
    __builtin_amdgcn_s_barrier();

    // ST = K-tile @ Q^T (swapped): ST[tn][tm] reg -> key=krow0+tn*16+quad*4+reg,
    // qrow = qrow0 + tm*16 + l15
    f32x4 ST[4][2];
#pragma unroll
    for (int i = 0; i < 4; i++)
#pragma unroll
      for (int j = 0; j < 2; j++) ST[i][j] = z4;
#pragma unroll
    for (int s = 0; s < 4; s++) {
      f16x8 bfr[4];
#pragma unroll
      for (int tn = 0; tn < 4; tn++) {
        int phys = (s * 4 + quad + l15) & 15;
        bfr[tn] = *(const f16x8*)&Ksb[(tn * 16 + l15) * 128 + phys * 8];
      }
      __builtin_amdgcn_s_setprio(1);
#pragma unroll
      for (int tn = 0; tn < 4; tn++)
#pragma unroll
        for (int tm = 0; tm < 2; tm++)
          ST[tn][tm] = __builtin_amdgcn_mfma_f32_16x16x32_f16(bfr[tn], qf[tm][s], ST[tn][tm], 0, 0, 0);
      __builtin_amdgcn_s_setprio(0);
    }

    // softmax (fixed-max, diag->1) + in-register P->A-frag pack
    f16x8 pa[2][2];   // [tm][ks]
#pragma unroll
    for (int tm = 0; tm < 2; tm++) {
      const int qg = qrow0 + tm * 16 + l15;
      float rs = 0.f;
      unsigned int H[4][2];
#pragma unroll
      for (int tn = 0; tn < 4; tn++) {
        float p[4];
#pragma unroll
        for (int reg = 0; reg < 4; reg++) {
          int kg = krow0 + tn * 16 + quad * 4 + reg;
          float v = (kg == qg) ? 1.f : __expf(ST[tn][tm][reg]);
          p[reg] = v;
          rs += v;
        }
        f16x2 h01 = {(f16)p[0], (f16)p[1]};
        f16x2 h23 = {(f16)p[2], (f16)p[3]};
        H[tn][0] = __builtin_bit_cast(unsigned int, h01);
        H[tn][1] = __builtin_bit_cast(unsigned int, h23);
      }
      rs += __shfl_xor(rs, 16);
      rs += __shfl_xor(rs, 32);
      lrow[tm] += rs;

      // pa[tm][ks] word w holds keys ks*32 + quad*8 + 2w,2w+1
#pragma unroll
      for (int ks = 0; ks < 2; ks++) {
        unsigned int a0 = H[ks * 2][0], a1 = H[ks * 2][1];
        unsigned int b0 = H[ks * 2 + 1][0], b1 = H[ks * 2 + 1][1];
        // in-place 32-lane half swap: a' = {a.lo, b.lo}, b' = {a.hi, b.hi}
        asm volatile("s_nop 1\n\tv_permlane32_swap_b32 %0, %1\n\ts_nop 1"
                     : "+v"(a0), "+v"(b0));
        asm volatile("s_nop 1\n\tv_permlane32_swap_b32 %0, %1\n\ts_nop 1"
                     : "+v"(a1), "+v"(b1));
        unsigned int c0 = (unsigned int)__shfl_xor((int)a0, 16);
        unsigned int c1 = (unsigned int)__shfl_xor((int)a1, 16);
        unsigned int d0 = (unsigned int)__shfl_xor((int)b0, 16);
        unsigned int d1 = (unsigned int)__shfl_xor((int)b1, 16);
        ui4 wv;
        wv[0] = qodd ? d0 : a0;
        wv[1] = qodd ? d1 : a1;
        wv[2] = qodd ? b0 : c0;
        wv[3] = qodd ? b1 : c1;
        pa[tm][ks] = __builtin_bit_cast(f16x8, wv);
      }
    }

    // O += P @ V
#pragma unroll
    for (int ks = 0; ks < 2; ks++) {
      __builtin_amdgcn_s_setprio(1);
#pragma unroll
      for (int tn = 0; tn < 8; tn++) {
        int phys = (ks * 4 + quad + r7) & 7;
        f16x8 vb = *(const f16x8*)&VTsb[(tn * 16 + l15) * 64 + phys * 8];
#pragma unroll
        for (int tm = 0; tm < 2; tm++)
          O[tm][tn] = __builtin_amdgcn_mfma_f32_16x16x32_f16(pa[tm][ks], vb, O[tm][tn], 0, 0, 0);
      }
      __builtin_amdgcn_s_setprio(0);
    }
    __builtin_amdgcn_s_barrier();
  }
#undef STAGE_KV_

  // epilogue: redistribute lrow (l15-layout -> quad*4+reg layout), O/l -> ctx
#pragma unroll
  for (int tm = 0; tm < 2; tm++)
#pragma unroll
    for (int reg = 0; reg < 4; reg++) {
      float lv = __shfl(lrow[tm], quad * 4 + reg);
      float inv = 1.f / lv;
      int row = bb * SEQ + qrow0 + tm * 16 + quad * 4 + reg;
#pragma unroll
      for (int tn = 0; tn < 8; tn++) {
        int col = h * 128 + tn * 16 + l15;
        ctx[(size_t)row * HDIM + col] = (f16)(O[tm][tn][reg] * inv);
      }
    }
}

// ---------------- launch ----------------

extern "C" void kernel_launch(void* const* d_in, const int* in_sizes, int n_in,
                              void* d_out, int out_size, void* d_ws, size_t ws_size,
                              hipStream_t stream) {
  (void)in_sizes; (void)n_in; (void)out_size; (void)ws_size;
  const float* x      = (const float*)d_in[0];
  const float* conv_w = (const float*)d_in[1];
  const float* conv_b = (const float*)d_in[2];
  const float* w1     = (const float*)d_in[3];
  const float* b1     = (const float*)d_in[4];
  const float* w2     = (const float*)d_in[5];
  const float* b2     = (const float*)d_in[6];
  const float* ln_g   = (const float*)d_in[7];
  const float* ln_b   = (const float*)d_in[8];
  const float* wq     = (const float*)d_in[9];
  const float* bq     = (const float*)d_in[10];
  const float* wk     = (const float*)d_in[11];
  const float* bk     = (const float*)d_in[12];
  const float* wv     = (const float*)d_in[13];
  const float* bv     = (const float*)d_in[14];
  const float* wo     = (const float*)d_in[15];
  const float* bo     = (const float*)d_in[16];
  const float* wp     = (const float*)d_in[17];
  const float* bp     = (const float*)d_in[18];
  float* out = (float*)d_out;

  char* ws = (char*)d_ws;
  size_t off = 0;
  auto alloc = [&](size_t bytes) {
    char* p = ws + off;
    off += (bytes + 255) & ~(size_t)255;
    return p;
  };
  float* cs    = (float*)alloc(8);
  f16* w1T     = (f16*)alloc((size_t)1024 * 512 * 2);
  f16* w2T     = (f16*)alloc((size_t)1024 * 1024 * 2);
  f16* qkvT    = (f16*)alloc((size_t)3072 * 1024 * 2);
  f16* wpT     = (f16*)alloc((size_t)1024 * 1024 * 2);
  f16* woh     = (f16*)alloc((size_t)1024 * 1024 * 2);
  f16* woPT    = (f16*)alloc((size_t)1024 * 1024 * 2);
  float* bqkv  = (float*)alloc((size_t)3072 * 4);
  float* bp2   = (float*)alloc((size_t)1024 * 4);
  float* part  = (float*)alloc((size_t)8 * 1024 * 4);
  float2* cpart = (float2*)alloc((size_t)8 * 3072 * 8);
  float2* c12   = (float2*)alloc((size_t)3072 * 8);
  float2* stats = (float2*)alloc((size_t)MR * 8);
  f16* qkvQK   = (f16*)alloc((size_t)MR * QK_LD * 2);  // 128 MB; front reused as xh
  f16* h1      = (f16*)alloc((size_t)MR * 1024 * 2);   // 64 MB; reused as vT
  f16* x_norm  = (f16*)alloc((size_t)MR * 1024 * 2);   // 64 MB; used only as ctx now
  f16* x_regh  = (f16*)alloc((size_t)MR * 1024 * 2);   // 64 MB (residual + LN-fold input)
  f16* xh = qkvQK;    // [32768,512] dead before qkvQK written
  f16* vT = h1;       // h1 dead after w2 gemm
  f16* ctx = x_norm;

  prep1<<<6797, 256, 0, stream>>>(
      conv_w, conv_b, cs, w1, w1T, w2, wq, wk, wv, wp, w2T, qkvT, wpT,
      wo, woh, bq, bk, bv, bqkv, bo, part, ln_g, ln_b, cpart);
  prep2<<<16400, 256, 0, stream>>>(x, cs, xh, part, bp, bp2, cpart, bqkv, c12);

  // woPT[n][k] = (wo@wp)[k][n]
  gemm_nt<4><<<dim3(64), 512, 0, stream>>>(wpT, woh, nullptr, (void*)woPT, 1024, 1024,
                                           nullptr, nullptr, nullptr, nullptr);

  gemm_nt<0><<<dim3(256 * 8), 512, 0, stream>>>(xh, w1T, b1, (void*)h1, 1024, 512,
                                                nullptr, nullptr, nullptr, nullptr);
  gemm_nt<1><<<dim3(256 * 8), 512, 0, stream>>>(h1, w2T, b2, (void*)x_regh, 1024, 1024,
                                                nullptr, nullptr, nullptr, nullptr);
  ln_stats<<<32768, 256, 0, stream>>>(x_regh, stats);
  // QKV with LN folded: A = x_regh; q,k -> qkvQK (LD 2048); v -> vT directly
  gemm_nt<6><<<dim3(256 * 24), 512, 0, stream>>>(x_regh, qkvT, nullptr, (void*)qkvQK, 3072, 1024,
                                                 nullptr, vT, c12, stats);
  attn_kernel<<<1024, 512, 0, stream>>>(qkvQK, vT, ctx);
  // fused wo+wp: out = ctx @ woP + bp2 + x_reg
  gemm_nt<5><<<dim3(256 * 8), 512, 0, stream>>>(ctx, woPT, bp2, (void*)out, 1024, 1024,
                                                x_regh, nullptr, nullptr, nullptr);
}